// Round 12
// baseline (216.991 us; speedup 1.0000x reference)
//
#include <hip/hip_runtime.h>
#include <cmath>

#define LN_EPS 1e-5f

typedef float  f32x4  __attribute__((ext_vector_type(4)));
typedef short  short8 __attribute__((ext_vector_type(8)));
typedef unsigned int uint4v __attribute__((ext_vector_type(4)));

// ws layout (uint4 units):
//   w1tf : 512   (temporal K-slice of w1, k=128..159, B-frag layout, bf16)
//   w2f  : 2048  (B-frag layout, bf16)
//   E1   : 1650  (50 x 132 f32: emb @ w1[:128] table, 128 cols + 4 pad)
//   tps  : 5 floats (uniform temporal-LN closed-form sums)
// E1 INSIGHT (round 10): only NUM_TYPES=50 distinct embedding rows exist, so
// emb@w1[:128] (45% of all MFMA FLOPs) is a 50x128 table computed once in
// prep (exact f32). Per tile the embedding contribution is an LDS gather;
// GEMM1 is just the K=32 temporal slice (8 MFMAs).
#define W1TF_U4 512
#define W2F_U4  2048
#define E1_U4   1650
#define WLDS_U4 2560   // w1tf + w2f staged to LDS

__device__ __forceinline__ unsigned short f32_bf16_rne(float f) {
    union { float f; unsigned u; } v; v.f = f;
    unsigned r = v.u + 0x7FFFu + ((v.u >> 16) & 1u);
    return (unsigned short)(r >> 16);
}

// packed f32->bf16 (RNE), 1 VALU op for 2 elements
__device__ __forceinline__ unsigned cvt_pk_bf16(float lo, float hi) {
    unsigned r;
    asm("v_cvt_pk_bf16_f32 %0, %1, %2" : "=v"(r) : "v"(lo), "v"(hi));
    return r;
}

// exact-erf GELU via Abramowitz&Stegun 7.1.26 (|err| <= 1.5e-7)
__device__ __forceinline__ float gelu_f(float x) {
    float ax = fabsf(x);
    float a  = ax * 0.70710678118654752f;          // |x|/sqrt(2)
    float t  = __builtin_amdgcn_rcpf(fmaf(0.3275911f, a, 1.0f));
    float p  = t * fmaf(t, fmaf(t, fmaf(t, fmaf(t, 1.061405429f, -1.453152027f),
                                        1.421413741f), -0.284496736f), 0.254829592f);
    float e  = __builtin_amdgcn_exp2f(-1.44269504089f * a * a);
    float E  = fmaf(-p, e, 1.0f);                  // erf(|x|/sqrt2)
    return 0.5f * fmaf(ax, E, x);                  // 0.5*(x + |x|*erf)
}

// DPP row-rotate add: sum over the 16-lane DPP row, all lanes get the result.
template<int C>
__device__ __forceinline__ float dpp_radd(float x) {
    int t = __builtin_amdgcn_update_dpp(0, __builtin_bit_cast(int, x), C, 0xF, 0xF, true);
    return x + __builtin_bit_cast(float, t);
}
__device__ __forceinline__ float red16(float x) {
    x = dpp_radd<0x128>(x);   // row_ror:8
    x = dpp_radd<0x124>(x);   // row_ror:4
    x = dpp_radd<0x122>(x);   // row_ror:2
    x = dpp_radd<0x121>(x);   // row_ror:1
    return x;
}

// -------- prep: build w1tf/w2f B-frags (bf16), E1 table (f32), temporal-LN
//          sums. Re-run every call.
__global__ void prep_kernel(const float* __restrict__ w1, const float* __restrict__ w2,
                            const float* __restrict__ emb,
                            const float* __restrict__ tp_w, const float* __restrict__ tp_b,
                            unsigned* __restrict__ ws) {
    const int tid = blockIdx.x * 256 + threadIdx.x;   // 8192 threads
    uint4v* w1tf = (uint4v*)ws;
    uint4v* w2f  = w1tf + W1TF_U4;
    float*  E1   = (float*)(w2f + W2F_U4);
    float*  tps  = E1 + 6600;

    for (int i = tid; i < W1TF_U4; i += 8192) {       // temporal slice frags
        const int lane = i & 63, nt = i >> 6;         // nt 0..7
        const int k0 = 128 + (lane >> 4) * 8, n = nt * 16 + (lane & 15);
        uint4v r;
        #pragma unroll
        for (int j2 = 0; j2 < 4; ++j2) {
            unsigned lo = f32_bf16_rne(w1[(k0 + 2 * j2) * 128 + n]);
            unsigned hi = f32_bf16_rne(w1[(k0 + 2 * j2 + 1) * 128 + n]);
            r[j2] = lo | (hi << 16);
        }
        w1tf[i] = r;
    }
    for (int i = tid; i < W2F_U4; i += 8192) {
        const int lane = i & 63, nt = (i >> 6) & 7, kt = i >> 9;
        const int k0 = kt * 32 + (lane >> 4) * 8, n = nt * 16 + (lane & 15);
        uint4v r;
        #pragma unroll
        for (int j2 = 0; j2 < 4; ++j2) {
            unsigned lo = f32_bf16_rne(w2[(k0 + 2 * j2) * 128 + n]);
            unsigned hi = f32_bf16_rne(w2[(k0 + 2 * j2 + 1) * 128 + n]);
            r[j2] = lo | (hi << 16);
        }
        w2f[i] = r;
    }
    // E1[t][n] = sum_k emb[t][k] * w1[k][n]  (f32 exact; coalesced over n)
    if (tid < 6400) {
        const int t = tid >> 7, n = tid & 127;
        float s = 0.f;
        #pragma unroll 4
        for (int k = 0; k < 128; ++k)
            s = fmaf(emb[t * 128 + k], w1[k * 128 + n], s);
        E1[t * 132 + n] = s;
    }
    if (tid == 0) {                                   // uniform temporal-LN sums
        float Sw = 0.f, Sb = 0.f, Sww = 0.f, Swb = 0.f, Sbb = 0.f;
        for (int j = 0; j < 32; ++j) {
            const float ww = tp_w[j], bb = tp_b[j];
            Sw += ww; Sb += bb; Sww += ww * ww; Swb += ww * bb; Sbb += bb * bb;
        }
        tps[0] = Sw; tps[1] = Sb; tps[2] = Sww; tps[3] = Swb; tps[4] = Sbb;
    }
}

// -------- main: 1024 threads = 16 waves; FOUR batch rows per block with a
//          flattened tile list (round 11); wave w takes t = w, w+16, ...
//
// OCCUPANCY (round 12): 16 waves/block, 1 block/CU (LDS 136 KB) = 4 waves/
// SIMD (50% cap, up from 37.5%). __launch_bounds__(1024,4) => 128-reg total
// budget; fits because acc/acc2 AGPR live ranges are disjoint (~32 peak) and
// register pools are GONE: the masked-pool is banked per tile into
// poolrow[4][128] via LDS atomicAdd (8 ds-adds from g==0 lanes after a
// 2-shfl g-reduce). The kernel is VALU-dependency-stall bound (round 11:
// VALUBusy 54% at 3 waves/SIMD); the 4th wave per SIMD fills those slots.
//
// REGISTER DISCIPLINE (rounds 2-5,7): phases strictly serial per tile;
// coefficients in LDS; empty-asm fences only (per-wave DS pipe in-order).
// SPILL TRIPWIRE: WRITE_SIZE > 50 MB => revert to round-11 (768,3) config.
__global__ __launch_bounds__(1024, 4) void encoder_mfma(
    const int*   __restrict__ tids,  const float* __restrict__ dates,
    const int*   __restrict__ lengths,
    const float* __restrict__ tp_w,  const float* __restrict__ tp_b,
    const float* __restrict__ tp_lnw,const float* __restrict__ tp_lnb,
    const float* __restrict__ b1,    const float* __restrict__ ln1w, const float* __restrict__ ln1b,
    const float* __restrict__ b2,    const float* __restrict__ ln2w, const float* __restrict__ ln2b,
    const unsigned* __restrict__ ws, float* __restrict__ out,
    int B, int L)
{
    __shared__ __align__(16) uint4v wlds[WLDS_U4];                // 40 KB: w1tf|w2f
    __shared__ __align__(16) float  E1lds[6600];                  // 26.4 KB
    // per-wave C->A transpose scratch (single m-tile): [wave][kt2][row64][j]
    __shared__ __align__(16) unsigned short a2[16][4][64][8];     // 64 KB
    __shared__ float poolrow[4][128];                             // 2 KB (atomic)
    __shared__ __align__(16) f32x4 tcoef[32];    // {tp_w, tp_b, tp_lnw, tp_lnb}
    __shared__ __align__(16) f32x4 ecoef1[128];  // {b1, ln1w, ln1b, -}
    __shared__ __align__(16) f32x4 ecoef2[128];  // {b2, ln2w, ln2b, -}

    const int tid = threadIdx.x;
    const int lane = tid & 63, w = tid >> 6;          // w in 0..15
    const int c = lane & 15, g = lane >> 4;
    const int b0 = blockIdx.x * 4;

    // ---- stage weights + E1 into LDS; zero pool accumulators ----
    for (int i = tid; i < WLDS_U4; i += 1024)
        wlds[i] = ((const uint4v*)ws)[i];
    for (int i = tid; i < E1_U4; i += 1024)
        ((uint4v*)E1lds)[i] = ((const uint4v*)ws)[WLDS_U4 + i];
    if (tid < 512) poolrow[tid >> 7][tid & 127] = 0.f;

    const float* tps = (const float*)((const uint4v*)ws + WLDS_U4 + E1_U4);

    if (tid < 32)  tcoef[tid]  = (f32x4){tp_w[tid], tp_b[tid], tp_lnw[tid], tp_lnb[tid]};
    if (tid < 128) {
        ecoef1[tid] = (f32x4){b1[tid], ln1w[tid], ln1b[tid], 0.f};
        ecoef2[tid] = (f32x4){b2[tid], ln2w[tid], ln2b[tid], 0.f};
    }
    __syncthreads();

    const float Sw = tps[0], Sb = tps[1], Sww = tps[2], Swb = tps[3], Sbb = tps[4];

    // flattened tile list over the block's 4 rows
    const int len0 = (b0 + 0 < B) ? min(max(lengths[b0 + 0], 0), L) : 0;
    const int len1 = (b0 + 1 < B) ? min(max(lengths[b0 + 1], 0), L) : 0;
    const int len2 = (b0 + 2 < B) ? min(max(lengths[b0 + 2], 0), L) : 0;
    const int len3 = (b0 + 3 < B) ? min(max(lengths[b0 + 3], 0), L) : 0;
    const int nt0 = (len0 + 15) >> 4, nt1 = (len1 + 15) >> 4;
    const int nt2 = (len2 + 15) >> 4, nt3 = (len3 + 15) >> 4;
    const int cum1 = nt0, cum2 = nt0 + nt1, cum3 = cum2 + nt2, T = cum3 + nt3;

    const int srl = lane ^ ((lane >> 3) & 3);          // swizzled GEMM2 read row

    for (int t = w; t < T; t += 16) {
        // wave-uniform (row, local tile) from flattened index
        int row, tl, lenr;
        if (t >= cum3)      { row = 3; tl = t - cum3; lenr = len3; }
        else if (t >= cum2) { row = 2; tl = t - cum2; lenr = len2; }
        else if (t >= cum1) { row = 1; tl = t - cum1; lenr = len1; }
        else                { row = 0; tl = t;        lenr = len0; }
        const int R0 = tl << 4;
        const long base = (long)(b0 + row) * L;

        const int pc = min(R0 + c, L - 1);
        const float d = dates[base + pc] * (1.f / 1825.f);
        // ids for this lane's C-layout rows (4g+r); group-uniform broadcast loads
        int idr[4];
        #pragma unroll
        for (int r = 0; r < 4; ++r)
            idr[r] = tids[base + min(R0 + 4 * g + r, L - 1)];

        // temporal A-frag (row = c, k-chunk = g*8..g*8+7); coeffs from LDS
        short8 tfrag;
        {
            const float tm = fmaf(d, Sw, Sb) * (1.f / 32.f);
            float tv = fmaf(d * d, Sww, fmaf(2.f * d, Swb, Sbb)) * (1.f / 32.f) - tm * tm;
            const float trs = rsqrtf(fmaxf(tv, 0.f) + LN_EPS);
            const int j0 = g * 8;
            uint4v r;
            #pragma unroll
            for (int j2 = 0; j2 < 4; ++j2) {
                const f32x4 t0 = tcoef[j0 + 2*j2];
                const f32x4 t1 = tcoef[j0 + 2*j2 + 1];
                const float y0 = fmaf((fmaf(d, t0[0], t0[1]) - tm) * trs, t0[2], t0[3]);
                const float y1 = fmaf((fmaf(d, t1[0], t1[1]) - tm) * trs, t1[2], t1[3]);
                r[j2] = cvt_pk_bf16(gelu_f(y0), gelu_f(y1));
            }
            union { uint4v u; short8 s; } cv; cv.u = r;
            tfrag = cv.s;
        }

        // ---- GEMM1: acc = E1 gather (emb@w1 table) + temporal K=32 MFMA ----
        f32x4 acc[8];
        #pragma unroll
        for (int r = 0; r < 4; ++r) {
            const int e1base = idr[r] * 132 + c;
            #pragma unroll
            for (int nt = 0; nt < 8; ++nt)
                acc[nt][r] = E1lds[e1base + nt * 16];
        }
        __builtin_amdgcn_s_setprio(1);
        #pragma unroll
        for (int nt = 0; nt < 8; ++nt) {
            const short8 bf = ((const short8*)wlds)[nt * 64 + lane];
            acc[nt] = __builtin_amdgcn_mfma_f32_16x16x32_bf16(tfrag, bf, acc[nt], 0, 0, 0);
        }
        __builtin_amdgcn_s_setprio(0);

        // ------- epilogue 1: +b1, LN1 (DPP), GELU -> bf16 a2[w] (swizzled) -------
        {
            f32x4 e1[8];
            #pragma unroll
            for (int nt = 0; nt < 8; ++nt) e1[nt] = ecoef1[nt * 16 + c];
            #pragma unroll
            for (int r = 0; r < 4; ++r) {
                float v[8], s = 0.f, q = 0.f;
                #pragma unroll
                for (int nt = 0; nt < 8; ++nt) {
                    v[nt] = acc[nt][r] + e1[nt][0];
                    s += v[nt]; q = fmaf(v[nt], v[nt], q);
                }
                s = red16(s); q = red16(q);
                const float mean = s * (1.f / 128.f);
                const float var  = fmaxf(q * (1.f / 128.f) - mean * mean, 0.f);
                const float rstd = rsqrtf(var + LN_EPS);
                const int mrow = 4 * g + r;
                #pragma unroll
                for (int n2 = 0; n2 < 4; ++n2) {
                    const float y0 = gelu_f(fmaf((v[2*n2]   - mean) * rstd, e1[2*n2][1],   e1[2*n2][2]));
                    const float y1 = gelu_f(fmaf((v[2*n2+1] - mean) * rstd, e1[2*n2+1][1], e1[2*n2+1][2]));
                    const unsigned pk = cvt_pk_bf16(y0, y1);
                    {
                        const int kcol  = (2*n2) * 16 + c;
                        const int row64 = ((kcol >> 3) & 3) * 16 + mrow;
                        const int srow  = row64 ^ ((row64 >> 3) & 3);
                        a2[w][kcol >> 5][srow][kcol & 7] = (unsigned short)(pk & 0xffffu);
                    }
                    {
                        const int kcol  = (2*n2+1) * 16 + c;
                        const int row64 = ((kcol >> 3) & 3) * 16 + mrow;
                        const int srow  = row64 ^ ((row64 >> 3) & 3);
                        a2[w][kcol >> 5][srow][kcol & 7] = (unsigned short)(pk >> 16);
                    }
                }
            }
        }

        asm volatile("" ::: "memory");                 // order a2 W->R (DS in-order)

        // ---------------- GEMM2: a2[w] @ w2f(LDS) ----------------
        f32x4 acc2[8];
        #pragma unroll
        for (int nt = 0; nt < 8; ++nt) acc2[nt] = (f32x4){0.f, 0.f, 0.f, 0.f};
        __builtin_amdgcn_s_setprio(1);
        #pragma unroll
        for (int kt2 = 0; kt2 < 4; ++kt2) {
            short8 af;
            __builtin_memcpy(&af, &a2[w][kt2][srl][0], 16);
            #pragma unroll
            for (int nt = 0; nt < 8; ++nt) {
                const short8 bf = ((const short8*)(wlds + W1TF_U4))[(kt2 * 8 + nt) * 64 + lane];
                acc2[nt] = __builtin_amdgcn_mfma_f32_16x16x32_bf16(af, bf, acc2[nt], 0, 0, 0);
            }
        }
        __builtin_amdgcn_s_setprio(0);

        asm volatile("" ::: "memory");                 // order a2 R -> next tile W

        // ---- epilogue 2: +b2, LN2, mask -> per-tile pool -> LDS atomicAdd ----
        {
            f32x4 e2[8];
            #pragma unroll
            for (int nt = 0; nt < 8; ++nt) e2[nt] = ecoef2[nt * 16 + c];
            float ptile[8];
            #pragma unroll
            for (int nt = 0; nt < 8; ++nt) ptile[nt] = 0.f;
            #pragma unroll
            for (int r = 0; r < 4; ++r) {
                float v[8], s = 0.f, q = 0.f;
                #pragma unroll
                for (int nt = 0; nt < 8; ++nt) {
                    v[nt] = acc2[nt][r] + e2[nt][0];
                    s += v[nt]; q = fmaf(v[nt], v[nt], q);
                }
                s = red16(s); q = red16(q);
                const float mean = s * (1.f / 128.f);
                const float var  = fmaxf(q * (1.f / 128.f) - mean * mean, 0.f);
                const float rstd = rsqrtf(var + LN_EPS);
                const float msk = ((R0 + 4 * g + r) < lenr) ? 1.f : 0.f;
                #pragma unroll
                for (int nt = 0; nt < 8; ++nt) {
                    const float y = fmaf((v[nt] - mean) * rstd, e2[nt][1], e2[nt][2]);
                    ptile[nt] = fmaf(y, msk, ptile[nt]);
                }
            }
            // reduce over g (2 shfl) then one LDS atomic per (nt) from g==0
            #pragma unroll
            for (int nt = 0; nt < 8; ++nt) {
                float tv = ptile[nt];
                tv += __shfl_xor(tv, 16);
                tv += __shfl_xor(tv, 32);
                ptile[nt] = tv;
            }
            if (g == 0) {
                #pragma unroll
                for (int nt = 0; nt < 8; ++nt)
                    atomicAdd(&poolrow[row][nt * 16 + c], ptile[nt]);
            }
        }
    }

    __syncthreads();
    if (tid < 512) {
        const int r4  = tid >> 7;                      // which row of the quad
        const int col = tid & 127;
        const int bo  = b0 + r4;
        if (bo < B) {
            const int lenb = min(max(lengths[bo], 0), L);
            out[bo * 128 + col] = (lenb > 0) ? poolrow[r4][col] / (float)lenb : 0.f;
        }
    }
}

extern "C" void kernel_launch(void* const* d_in, const int* in_sizes, int n_in,
                              void* d_out, int out_size, void* d_ws, size_t ws_size,
                              hipStream_t stream) {
    const int*   tids    = (const int*)  d_in[0];
    const float* dates   = (const float*)d_in[1];
    const int*   lengths = (const int*)  d_in[2];
    const float* emb     = (const float*)d_in[3];
    const float* tp_w    = (const float*)d_in[4];
    const float* tp_b    = (const float*)d_in[5];
    const float* tp_lnw  = (const float*)d_in[6];
    const float* tp_lnb  = (const float*)d_in[7];
    const float* w1      = (const float*)d_in[8];
    const float* b1      = (const float*)d_in[9];
    const float* ln1w    = (const float*)d_in[10];
    const float* ln1b    = (const float*)d_in[11];
    const float* w2      = (const float*)d_in[12];
    const float* b2      = (const float*)d_in[13];
    const float* ln2w    = (const float*)d_in[14];
    const float* ln2b    = (const float*)d_in[15];
    float* out = (float*)d_out;

    const int B = in_sizes[2];
    const int L = in_sizes[0] / B;

    hipLaunchKernelGGL(prep_kernel, dim3(32), dim3(256), 0, stream,
                       w1, w2, emb, tp_w, tp_b, (unsigned*)d_ws);
    hipLaunchKernelGGL(encoder_mfma, dim3((B + 3) / 4), dim3(1024), 0, stream,
                       tids, dates, lengths, tp_w, tp_b, tp_lnw, tp_lnb,
                       b1, ln1w, ln1b, b2, ln2w, ln2b,
                       (const unsigned*)d_ws, out, B, L);
}